// Round 2
// baseline (294.969 us; speedup 1.0000x reference)
//
#include <hip/hip_runtime.h>
#include <hip/hip_bf16.h>
#include <stdint.h>

#define NHEADS 16
#define DKH    64
#define BB     2
#define SS     2048
#define DM     1024
#define MROWS  (BB * SS)   // 4096

typedef __attribute__((ext_vector_type(8))) short bf8_t;   // 8 bf16 in 4 VGPRs
typedef __attribute__((ext_vector_type(4))) float f4_t;    // MFMA accum
typedef unsigned short u16;

__device__ __forceinline__ u16 f2bf(float f) {
    union { float f; uint32_t u; } v; v.f = f;
    return (u16)((v.u + 0x7fffu + ((v.u >> 16) & 1u)) >> 16);  // RNE
}

__device__ __forceinline__ void async_copy16(void* lds, const void* g) {
    __builtin_amdgcn_global_load_lds(
        (__attribute__((address_space(1))) void*)(void*)g,
        (__attribute__((address_space(3))) void*)lds, 16, 0, 0);
}

// ---------------- f32 -> bf16 elementwise ----------------
__global__ void k_cvt(const float* __restrict__ in, u16* __restrict__ out, int n4) {
    int stride = gridDim.x * blockDim.x;
    for (int i = blockIdx.x * blockDim.x + threadIdx.x; i < n4; i += stride) {
        float4 v = ((const float4*)in)[i];
        ushort4 o;
        o.x = f2bf(v.x); o.y = f2bf(v.y); o.z = f2bf(v.z); o.w = f2bf(v.w);
        ((ushort4*)out)[i] = o;
    }
}

// ---------------- W (K x N f32) -> Wt (N x K bf16) ----------------
__global__ void k_transpose(const float* __restrict__ W, u16* __restrict__ Wt, int K, int N) {
    __shared__ float tile[32][33];
    int n0 = blockIdx.x * 32, k0 = blockIdx.y * 32;
    int tx = threadIdx.x & 31, ty = threadIdx.x >> 5;
    #pragma unroll
    for (int r = ty; r < 32; r += 8)
        tile[r][tx] = W[(size_t)(k0 + r) * N + n0 + tx];
    __syncthreads();
    #pragma unroll
    for (int r = ty; r < 32; r += 8)
        Wt[(size_t)(n0 + r) * K + k0 + tx] = f2bf(tile[tx][r]);
}

// ---------------- bf16 GEMM: C = A(MxK) * Bt(NxK)^T + bias ----------------
// MODE 0: epilogue scatters to Q[b,h,s,dk], K[b,h,s,dk], Vt[b,h,dk,s] (bf16)
// MODE 1: epilogue writes fp32 C row-major
template<int MODE>
__global__ __launch_bounds__(256) void k_gemm(
    const u16* __restrict__ A, const u16* __restrict__ Bt,
    const float* __restrict__ bias,
    u16* __restrict__ q_out, u16* __restrict__ k_out, u16* __restrict__ vt_out,
    float* __restrict__ f_out,
    int N, int K)
{
    __shared__ u16 As[128 * 32];
    __shared__ u16 Bs[128 * 32];
    const int m0 = blockIdx.y * 128, n0 = blockIdx.x * 128;
    const int tid = threadIdx.x;
    const int w = tid >> 6, l = tid & 63;
    const int lr = l >> 2, lc = (l & 3) * 8;     // staging: row-in-chunk, col offset
    const int fr = l & 15, fk = (l >> 4) * 8;    // fragment row / k offset
    const int wm = (w >> 1) * 64, wn = (w & 1) * 64;
    f4_t acc[4][4] = {};

    for (int kt = 0; kt < K; kt += 32) {
        #pragma unroll
        for (int cc = 0; cc < 2; ++cc) {
            const int c = w + cc * 4;   // 16-row chunk id (0..7)
            async_copy16(As + c * 512, A  + (size_t)(m0 + c * 16 + lr) * K + kt + lc);
            async_copy16(Bs + c * 512, Bt + (size_t)(n0 + c * 16 + lr) * K + kt + lc);
        }
        __syncthreads();
        bf8_t af[4], bfr[4];
        #pragma unroll
        for (int mf = 0; mf < 4; ++mf)
            af[mf] = *(const bf8_t*)&As[(wm + mf * 16 + fr) * 32 + fk];
        #pragma unroll
        for (int nf = 0; nf < 4; ++nf)
            bfr[nf] = *(const bf8_t*)&Bs[(wn + nf * 16 + fr) * 32 + fk];
        #pragma unroll
        for (int mf = 0; mf < 4; ++mf)
            #pragma unroll
            for (int nf = 0; nf < 4; ++nf)
                acc[mf][nf] = __builtin_amdgcn_mfma_f32_16x16x32_bf16(af[mf], bfr[nf], acc[mf][nf], 0, 0, 0);
        __syncthreads();
    }

    #pragma unroll
    for (int mf = 0; mf < 4; ++mf)
      #pragma unroll
      for (int nf = 0; nf < 4; ++nf)
        #pragma unroll
        for (int j = 0; j < 4; ++j) {
            const int m = m0 + wm + mf * 16 + (l >> 4) * 4 + j;
            const int n = n0 + wn + nf * 16 + (l & 15);
            float v = acc[mf][nf][j] + bias[n];
            if (MODE == 0) {
                const int h = n / 192, rem = n - h * 192;
                const int which = rem >> 6, dd = rem & 63;
                const int b = m >> 11, s = m & (SS - 1);
                const u16 bv = f2bf(v);
                const size_t qk_idx = ((size_t)(b * NHEADS + h) * SS + s) * DKH + dd;
                if (which == 0)      q_out[qk_idx] = bv;
                else if (which == 1) k_out[qk_idx] = bv;
                else                 vt_out[((size_t)(b * NHEADS + h) * DKH + dd) * SS + s] = bv;
            } else {
                f_out[(size_t)m * N + n] = v;
            }
        }
}

// ---------------- flash attention ----------------
__device__ __forceinline__ float red16_max(float v) {
    v = fmaxf(v, __shfl_xor(v, 1));
    v = fmaxf(v, __shfl_xor(v, 2));
    v = fmaxf(v, __shfl_xor(v, 4));
    v = fmaxf(v, __shfl_xor(v, 8));
    return v;
}
__device__ __forceinline__ float red16_sum(float v) {
    v += __shfl_xor(v, 1);
    v += __shfl_xor(v, 2);
    v += __shfl_xor(v, 4);
    v += __shfl_xor(v, 8);
    return v;
}

__global__ __launch_bounds__(256) void k_attn(
    const u16* __restrict__ Qg, const u16* __restrict__ Kg, const u16* __restrict__ Vtg,
    u16* __restrict__ ctx)
{
    __shared__ u16 Ks[64 * 72];        // [key][dk], rows padded to 72
    __shared__ u16 Vs[64 * 72];        // [dk][key], rows padded to 72
    __shared__ u16 Ps[4][32 * 72];     // per-wave P round-trip buffer
    const int bh = blockIdx.x;         // b*16 + h
    const int qt = blockIdx.y;         // q tile of 128
    const int tid = threadIdx.x, w = tid >> 6, l = tid & 63;
    const int fr = l & 15, fk = (l >> 4) * 8, fj = (l >> 4) * 4;
    const int q0 = qt * 128 + w * 32;  // this wave's 32 q rows
    const u16* Qb = Qg  + (size_t)bh * SS * DKH;
    const u16* Kb = Kg  + (size_t)bh * SS * DKH;
    const u16* Vb = Vtg + (size_t)bh * DKH * SS;

    bf8_t qf[2][2];
    #pragma unroll
    for (int mf = 0; mf < 2; ++mf)
      #pragma unroll
      for (int kh = 0; kh < 2; ++kh)
        qf[mf][kh] = *(const bf8_t*)(Qb + (size_t)(q0 + mf * 16 + fr) * DKH + kh * 32 + fk);

    float mrow[2][4], lrow[2][4];
    f4_t o[2][4] = {};
    #pragma unroll
    for (int mf = 0; mf < 2; ++mf)
      #pragma unroll
      for (int j = 0; j < 4; ++j) { mrow[mf][j] = -__builtin_inff(); lrow[mf][j] = 0.f; }

    for (int kv = 0; kv < SS; kv += 64) {
        #pragma unroll
        for (int it = 0; it < 2; ++it) {
            const int c = tid + it * 256;           // 512 chunks of 8 bf16
            const int r = c >> 3, c8 = (c & 7) * 8;
            *(uint4*)&Ks[r * 72 + c8] = *(const uint4*)(Kb + (size_t)(kv + r) * DKH + c8);
            *(uint4*)&Vs[r * 72 + c8] = *(const uint4*)(Vb + (size_t)r * SS + kv + c8);
        }
        __syncthreads();

        // S = Q K^T
        f4_t sa[2][4] = {};
        #pragma unroll
        for (int nf = 0; nf < 4; ++nf)
          #pragma unroll
          for (int kh = 0; kh < 2; ++kh) {
            const bf8_t kb = *(const bf8_t*)&Ks[(nf * 16 + fr) * 72 + kh * 32 + fk];
            #pragma unroll
            for (int mf = 0; mf < 2; ++mf)
                sa[mf][nf] = __builtin_amdgcn_mfma_f32_16x16x32_bf16(qf[mf][kh], kb, sa[mf][nf], 0, 0, 0);
          }

        // online softmax (rows live in lane groups of 16)
        #pragma unroll
        for (int mf = 0; mf < 2; ++mf) {
            float mnew[4], sc[4], ps[4];
            #pragma unroll
            for (int j = 0; j < 4; ++j) {
                float t = fmaxf(fmaxf(sa[mf][0][j], sa[mf][1][j]),
                                fmaxf(sa[mf][2][j], sa[mf][3][j]));
                t = red16_max(t * 0.125f);
                mnew[j] = fmaxf(mrow[mf][j], t);
                sc[j] = __expf(mrow[mf][j] - mnew[j]);
                ps[j] = 0.f;
            }
            #pragma unroll
            for (int nf = 0; nf < 4; ++nf)
              #pragma unroll
              for (int j = 0; j < 4; ++j) {
                float p = __expf(sa[mf][nf][j] * 0.125f - mnew[j]);
                sa[mf][nf][j] = p;
                ps[j] += p;
              }
            #pragma unroll
            for (int j = 0; j < 4; ++j) {
                ps[j] = red16_sum(ps[j]);
                lrow[mf][j] = lrow[mf][j] * sc[j] + ps[j];
                mrow[mf][j] = mnew[j];
            }
            #pragma unroll
            for (int df = 0; df < 4; ++df)
              #pragma unroll
              for (int j = 0; j < 4; ++j)
                o[mf][df][j] *= sc[j];
            // P (C-layout) -> LDS for A-layout reload
            #pragma unroll
            for (int nf = 0; nf < 4; ++nf)
              #pragma unroll
              for (int j = 0; j < 4; ++j)
                Ps[w][(mf * 16 + fj + j) * 72 + nf * 16 + fr] = f2bf(sa[mf][nf][j]);
        }

        // O += P V
        #pragma unroll
        for (int mf = 0; mf < 2; ++mf)
          #pragma unroll
          for (int kf = 0; kf < 2; ++kf) {
            const bf8_t pa = *(const bf8_t*)&Ps[w][(mf * 16 + fr) * 72 + kf * 32 + fk];
            #pragma unroll
            for (int df = 0; df < 4; ++df) {
                const bf8_t vv = *(const bf8_t*)&Vs[(df * 16 + fr) * 72 + kf * 32 + fk];
                o[mf][df] = __builtin_amdgcn_mfma_f32_16x16x32_bf16(pa, vv, o[mf][df], 0, 0, 0);
            }
          }
        __syncthreads();
    }

    const int b = bh >> 4, h = bh & 15;
    #pragma unroll
    for (int mf = 0; mf < 2; ++mf)
      #pragma unroll
      for (int df = 0; df < 4; ++df)
        #pragma unroll
        for (int j = 0; j < 4; ++j) {
            const int s = q0 + mf * 16 + fj + j;
            const int dd = df * 16 + fr;
            float v = o[mf][df][j] / lrow[mf][j];
            ctx[((size_t)(b * SS + s)) * DM + h * DKH + dd] = f2bf(v);
        }
}

// ---------------- launcher ----------------
extern "C" void kernel_launch(void* const* d_in, const int* in_sizes, int n_in,
                              void* d_out, int out_size, void* d_ws, size_t ws_size,
                              hipStream_t stream)
{
    const float* x     = (const float*)d_in[0];
    const float* W_qkv = (const float*)d_in[1];
    const float* b_qkv = (const float*)d_in[2];
    const float* W_o   = (const float*)d_in[3];
    const float* b_o   = (const float*)d_in[4];
    float* out = (float*)d_out;

    char* ws = (char*)d_ws;
    u16* xb   = (u16*)(ws);                                   // 4096x1024  (8 MB)
    u16* Wqkt = (u16*)(ws + 8388608);                         // 3072x1024  (6 MB)
    u16* Wot  = (u16*)(ws + 8388608 + 6291456);               // 1024x1024  (2 MB)
    u16* Qg   = (u16*)(ws + 16777216);                        // 32x2048x64 (8 MB)
    u16* Kg   = Qg  + 4194304;
    u16* Vtg  = Kg  + 4194304;
    u16* ctx  = xb;                                           // alias: xb dead after k_gemm<0>

    k_cvt<<<1024, 256, 0, stream>>>(x, xb, (MROWS * DM) / 4);
    k_transpose<<<dim3(3 * DM / 32, DM / 32), 256, 0, stream>>>(W_qkv, Wqkt, DM, 3 * DM);
    k_transpose<<<dim3(DM / 32, DM / 32), 256, 0, stream>>>(W_o, Wot, DM, DM);
    k_gemm<0><<<dim3(3 * DM / 128, MROWS / 128), 256, 0, stream>>>(
        xb, Wqkt, b_qkv, Qg, Kg, Vtg, nullptr, 3 * DM, DM);
    k_attn<<<dim3(BB * NHEADS, SS / 128), 256, 0, stream>>>(Qg, Kg, Vtg, ctx);
    k_gemm<1><<<dim3(DM / 128, MROWS / 128), 256, 0, stream>>>(
        ctx, Wot, b_o, nullptr, nullptr, nullptr, out, DM, DM);
}

// Round 3
// 265.285 us; speedup vs baseline: 1.1119x; 1.1119x over previous
//
#include <hip/hip_runtime.h>
#include <hip/hip_bf16.h>
#include <stdint.h>

#define NHEADS 16
#define DKH    64
#define BB     2
#define SS     2048
#define DM     1024
#define MROWS  (BB * SS)   // 4096

typedef __attribute__((ext_vector_type(8))) short bf8_t;   // 8 bf16 in 4 VGPRs
typedef __attribute__((ext_vector_type(4))) float f4_t;    // MFMA accum
typedef unsigned short u16;

__device__ __forceinline__ u16 f2bf(float f) {
    union { float f; uint32_t u; } v; v.f = f;
    return (u16)((v.u + 0x7fffu + ((v.u >> 16) & 1u)) >> 16);  // RNE
}

__device__ __forceinline__ float fexp2(float x) {
#if __has_builtin(__builtin_amdgcn_exp2f)
    return __builtin_amdgcn_exp2f(x);
#else
    return __expf(x * 0.69314718056f);
#endif
}

__device__ __forceinline__ void async_copy16(void* lds, const void* g) {
    __builtin_amdgcn_global_load_lds(
        (__attribute__((address_space(1))) void*)(void*)g,
        (__attribute__((address_space(3))) void*)lds, 16, 0, 0);
}

// ---------------- f32 -> bf16 elementwise ----------------
__global__ void k_cvt(const float* __restrict__ in, u16* __restrict__ out, int n4) {
    int stride = gridDim.x * blockDim.x;
    for (int i = blockIdx.x * blockDim.x + threadIdx.x; i < n4; i += stride) {
        float4 v = ((const float4*)in)[i];
        ushort4 o;
        o.x = f2bf(v.x); o.y = f2bf(v.y); o.z = f2bf(v.z); o.w = f2bf(v.w);
        ((ushort4*)out)[i] = o;
    }
}

// ---------------- W (K x N f32) -> Wt (N x K bf16) ----------------
__global__ void k_transpose(const float* __restrict__ W, u16* __restrict__ Wt, int K, int N) {
    __shared__ float tile[32][33];
    int n0 = blockIdx.x * 32, k0 = blockIdx.y * 32;
    int tx = threadIdx.x & 31, ty = threadIdx.x >> 5;
    #pragma unroll
    for (int r = ty; r < 32; r += 8)
        tile[r][tx] = W[(size_t)(k0 + r) * N + n0 + tx];
    __syncthreads();
    #pragma unroll
    for (int r = ty; r < 32; r += 8)
        Wt[(size_t)(n0 + r) * K + k0 + tx] = f2bf(tile[tx][r]);
}

// ---------------- bf16 GEMM: C = A(MxK) * Bt(NxK)^T + bias ----------------
template<int MODE>
__global__ __launch_bounds__(256) void k_gemm(
    const u16* __restrict__ A, const u16* __restrict__ Bt,
    const float* __restrict__ bias,
    u16* __restrict__ q_out, u16* __restrict__ k_out, u16* __restrict__ vt_out,
    float* __restrict__ f_out,
    int N, int K)
{
    __shared__ u16 As[128 * 32];
    __shared__ u16 Bs[128 * 32];
    const int m0 = blockIdx.y * 128, n0 = blockIdx.x * 128;
    const int tid = threadIdx.x;
    const int w = tid >> 6, l = tid & 63;
    const int lr = l >> 2, lc = (l & 3) * 8;
    const int fr = l & 15, fk = (l >> 4) * 8;
    const int wm = (w >> 1) * 64, wn = (w & 1) * 64;
    f4_t acc[4][4] = {};

    for (int kt = 0; kt < K; kt += 32) {
        #pragma unroll
        for (int cc = 0; cc < 2; ++cc) {
            const int c = w + cc * 4;
            async_copy16(As + c * 512, A  + (size_t)(m0 + c * 16 + lr) * K + kt + lc);
            async_copy16(Bs + c * 512, Bt + (size_t)(n0 + c * 16 + lr) * K + kt + lc);
        }
        __syncthreads();
        bf8_t af[4], bfr[4];
        #pragma unroll
        for (int mf = 0; mf < 4; ++mf)
            af[mf] = *(const bf8_t*)&As[(wm + mf * 16 + fr) * 32 + fk];
        #pragma unroll
        for (int nf = 0; nf < 4; ++nf)
            bfr[nf] = *(const bf8_t*)&Bs[(wn + nf * 16 + fr) * 32 + fk];
        #pragma unroll
        for (int mf = 0; mf < 4; ++mf)
            #pragma unroll
            for (int nf = 0; nf < 4; ++nf)
                acc[mf][nf] = __builtin_amdgcn_mfma_f32_16x16x32_bf16(af[mf], bfr[nf], acc[mf][nf], 0, 0, 0);
        __syncthreads();
    }

    #pragma unroll
    for (int mf = 0; mf < 4; ++mf)
      #pragma unroll
      for (int nf = 0; nf < 4; ++nf)
        #pragma unroll
        for (int j = 0; j < 4; ++j) {
            const int m = m0 + wm + mf * 16 + (l >> 4) * 4 + j;
            const int n = n0 + wn + nf * 16 + (l & 15);
            float v = acc[mf][nf][j] + bias[n];
            if (MODE == 0) {
                const int h = n / 192, rem = n - h * 192;
                const int which = rem >> 6, dd = rem & 63;
                const int b = m >> 11, s = m & (SS - 1);
                const u16 bv = f2bf(v);
                const size_t qk_idx = ((size_t)(b * NHEADS + h) * SS + s) * DKH + dd;
                if (which == 0)      q_out[qk_idx] = bv;
                else if (which == 1) k_out[qk_idx] = bv;
                else                 vt_out[((size_t)(b * NHEADS + h) * DKH + dd) * SS + s] = bv;
            } else {
                f_out[(size_t)m * N + n] = v;
            }
        }
}

// ---------------- flash attention ----------------
// Block: 4 waves x 16 q-rows = 64 q rows. Grid (32 bh, SS/64).
// LDS tiles are [row][8 slots of 16B], slot XOR-swizzled by (row&7).
__device__ __forceinline__ float red16_max(float v) {
    v = fmaxf(v, __shfl_xor(v, 1));
    v = fmaxf(v, __shfl_xor(v, 2));
    v = fmaxf(v, __shfl_xor(v, 4));
    v = fmaxf(v, __shfl_xor(v, 8));
    return v;
}
__device__ __forceinline__ float red16_sum(float v) {
    v += __shfl_xor(v, 1);
    v += __shfl_xor(v, 2);
    v += __shfl_xor(v, 4);
    v += __shfl_xor(v, 8);
    return v;
}

#define SCL 0.180336880f   // (1/8) * log2(e)

__global__ __launch_bounds__(256) void k_attn(
    const u16* __restrict__ Qg, const u16* __restrict__ Kg, const u16* __restrict__ Vtg,
    u16* __restrict__ ctx)
{
    __shared__ u16 Ks[64 * 64];        // [key][dk], swizzled
    __shared__ u16 Vs[64 * 64];        // [dk][key], swizzled
    __shared__ u16 Ps[4][16 * 64];     // per-wave P, swizzled
    const int bh = blockIdx.x;
    const int qt = blockIdx.y;
    const int tid = threadIdx.x, w = tid >> 6, l = tid & 63;
    const int fr = l & 15, fq = l >> 4;       // fragment row / quad
    const int q0 = qt * 64 + w * 16;          // this wave's 16 q rows
    const u16* Qb = Qg  + (size_t)bh * SS * DKH;
    const u16* Kb = Kg  + (size_t)bh * SS * DKH;
    const u16* Vb = Vtg + (size_t)bh * DKH * SS;

    bf8_t qf[2];
    #pragma unroll
    for (int kh = 0; kh < 2; ++kh)
        qf[kh] = *(const bf8_t*)(Qb + (size_t)(q0 + fr) * DKH + kh * 32 + fq * 8);

    float mrow[4], lrow[4];
    f4_t o[4] = {};
    #pragma unroll
    for (int j = 0; j < 4; ++j) { mrow[j] = -__builtin_inff(); lrow[j] = 0.f; }

    for (int kv = 0; kv < SS; kv += 64) {
        #pragma unroll
        for (int it = 0; it < 2; ++it) {
            const int c = tid + it * 256;      // 512 chunks of 8 bf16 per tile
            const int r = c >> 3, sl = c & 7;
            const int dsl = sl ^ (r & 7);
            *(uint4*)&Ks[r * 64 + dsl * 8] = *(const uint4*)(Kb + (size_t)(kv + r) * DKH + sl * 8);
            *(uint4*)&Vs[r * 64 + dsl * 8] = *(const uint4*)(Vb + (size_t)r * SS + kv + sl * 8);
        }
        __syncthreads();

        // S = Q K^T   (C layout: qrow = fq*4+j, key = nf*16+fr)
        f4_t sa[4] = {};
        #pragma unroll
        for (int nf = 0; nf < 4; ++nf)
          #pragma unroll
          for (int kh = 0; kh < 2; ++kh) {
            const int row = nf * 16 + fr;
            const int dsl = (kh * 4 + fq) ^ (fr & 7);
            const bf8_t kb = *(const bf8_t*)&Ks[row * 64 + dsl * 8];
            sa[nf] = __builtin_amdgcn_mfma_f32_16x16x32_bf16(qf[kh], kb, sa[nf], 0, 0, 0);
          }

        // online softmax in log2 domain, defer-max (THR=8)
        float t[4];
        #pragma unroll
        for (int j = 0; j < 4; ++j) {
            float x = fmaxf(fmaxf(sa[0][j], sa[1][j]), fmaxf(sa[2][j], sa[3][j]));
            t[j] = red16_max(x * SCL);
        }
        bool grow = false;
        #pragma unroll
        for (int j = 0; j < 4; ++j) grow |= (t[j] > mrow[j] + 8.f);
        if (__any(grow)) {
            #pragma unroll
            for (int j = 0; j < 4; ++j) {
                float mnew = fmaxf(mrow[j], t[j]);
                float sc = fexp2(mrow[j] - mnew);
                lrow[j] *= sc;
                mrow[j] = mnew;
                #pragma unroll
                for (int df = 0; df < 4; ++df) o[df][j] *= sc;
            }
        }
        float ps[4] = {0.f, 0.f, 0.f, 0.f};
        #pragma unroll
        for (int nf = 0; nf < 4; ++nf)
          #pragma unroll
          for (int j = 0; j < 4; ++j) {
            float p = fexp2(sa[nf][j] * SCL - mrow[j]);
            sa[nf][j] = p;
            ps[j] += p;
          }
        #pragma unroll
        for (int j = 0; j < 4; ++j) lrow[j] += red16_sum(ps[j]);

        // P (C-layout) -> LDS (swizzled) for A-layout reload
        #pragma unroll
        for (int nf = 0; nf < 4; ++nf)
          #pragma unroll
          for (int j = 0; j < 4; ++j) {
            const int qrow = fq * 4 + j;
            const int col = nf * 16 + fr;
            const int dsl = ((col >> 3) ^ (qrow & 7));
            Ps[w][qrow * 64 + dsl * 8 + (col & 7)] = f2bf(sa[nf][j]);
          }

        // O += P V
        #pragma unroll
        for (int kf = 0; kf < 2; ++kf) {
            const int pdsl = (kf * 4 + fq) ^ (fr & 7);
            const bf8_t pa = *(const bf8_t*)&Ps[w][fr * 64 + pdsl * 8];
            #pragma unroll
            for (int df = 0; df < 4; ++df) {
                const int row = df * 16 + fr;
                const int vdsl = (kf * 4 + fq) ^ (fr & 7);
                const bf8_t vv = *(const bf8_t*)&Vs[row * 64 + vdsl * 8];
                o[df] = __builtin_amdgcn_mfma_f32_16x16x32_bf16(pa, vv, o[df], 0, 0, 0);
            }
        }
        __syncthreads();
    }

    const int b = bh >> 4, h = bh & 15;
    #pragma unroll
    for (int df = 0; df < 4; ++df)
      #pragma unroll
      for (int j = 0; j < 4; ++j) {
        const int s = q0 + fq * 4 + j;
        const int dd = df * 16 + fr;
        float v = o[df][j] / lrow[j];
        ctx[((size_t)(b * SS + s)) * DM + h * DKH + dd] = f2bf(v);
      }
}

// ---------------- launcher ----------------
extern "C" void kernel_launch(void* const* d_in, const int* in_sizes, int n_in,
                              void* d_out, int out_size, void* d_ws, size_t ws_size,
                              hipStream_t stream)
{
    const float* x     = (const float*)d_in[0];
    const float* W_qkv = (const float*)d_in[1];
    const float* b_qkv = (const float*)d_in[2];
    const float* W_o   = (const float*)d_in[3];
    const float* b_o   = (const float*)d_in[4];
    float* out = (float*)d_out;

    char* ws = (char*)d_ws;
    u16* xb   = (u16*)(ws);                                   // 4096x1024  (8 MB)
    u16* Wqkt = (u16*)(ws + 8388608);                         // 3072x1024  (6 MB)
    u16* Wot  = (u16*)(ws + 8388608 + 6291456);               // 1024x1024  (2 MB)
    u16* Qg   = (u16*)(ws + 16777216);                        // 32x2048x64 (8 MB)
    u16* Kg   = Qg  + 4194304;
    u16* Vtg  = Kg  + 4194304;
    u16* ctx  = xb;                                           // alias: xb dead after k_gemm<0>

    k_cvt<<<1024, 256, 0, stream>>>(x, xb, (MROWS * DM) / 4);
    k_transpose<<<dim3(3 * DM / 32, DM / 32), 256, 0, stream>>>(W_qkv, Wqkt, DM, 3 * DM);
    k_transpose<<<dim3(DM / 32, DM / 32), 256, 0, stream>>>(W_o, Wot, DM, DM);
    k_gemm<0><<<dim3(3 * DM / 128, MROWS / 128), 256, 0, stream>>>(
        xb, Wqkt, b_qkv, Qg, Kg, Vtg, nullptr, 3 * DM, DM);
    k_attn<<<dim3(BB * NHEADS, SS / 64), 256, 0, stream>>>(Qg, Kg, Vtg, ctx);
    k_gemm<1><<<dim3(DM / 128, MROWS / 128), 256, 0, stream>>>(
        ctx, Wot, b_o, nullptr, nullptr, nullptr, out, DM, DM);
}

// Round 4
// 230.103 us; speedup vs baseline: 1.2819x; 1.1529x over previous
//
#include <hip/hip_runtime.h>
#include <hip/hip_bf16.h>
#include <stdint.h>

#define NHEADS 16
#define DKH    64
#define BB     2
#define SS     2048
#define DM     1024
#define MROWS  (BB * SS)   // 4096

typedef __attribute__((ext_vector_type(8))) short bf8_t;   // 8 bf16 in 4 VGPRs
typedef __attribute__((ext_vector_type(4))) float f4_t;    // MFMA accum
typedef unsigned short u16;
typedef uint32_t u32;

__device__ __forceinline__ u16 f2bf(float f) {
    union { float f; u32 u; } v; v.f = f;
    return (u16)((v.u + 0x7fffu + ((v.u >> 16) & 1u)) >> 16);  // RNE
}

__device__ __forceinline__ float fexp2(float x) {
#if __has_builtin(__builtin_amdgcn_exp2f)
    return __builtin_amdgcn_exp2f(x);
#else
    return __expf(x * 0.69314718056f);
#endif
}

__device__ __forceinline__ void async_copy16(void* lds, const void* g) {
    __builtin_amdgcn_global_load_lds(
        (__attribute__((address_space(1))) void*)(void*)g,
        (__attribute__((address_space(3))) void*)lds, 16, 0, 0);
}

#define MFMA32(a, b, c) __builtin_amdgcn_mfma_f32_16x16x32_bf16(a, b, c, 0, 0, 0)

// ---------------- f32 -> bf16 elementwise ----------------
__global__ void k_cvt(const float* __restrict__ in, u16* __restrict__ out, int n4) {
    int stride = gridDim.x * blockDim.x;
    for (int i = blockIdx.x * blockDim.x + threadIdx.x; i < n4; i += stride) {
        float4 v = ((const float4*)in)[i];
        ushort4 o;
        o.x = f2bf(v.x); o.y = f2bf(v.y); o.z = f2bf(v.z); o.w = f2bf(v.w);
        ((ushort4*)out)[i] = o;
    }
}

// ---------------- W (K x N f32) -> Wt (N x K bf16) ----------------
__global__ void k_transpose(const float* __restrict__ W, u16* __restrict__ Wt, int K, int N) {
    __shared__ float tile[32][33];
    int n0 = blockIdx.x * 32, k0 = blockIdx.y * 32;
    int tx = threadIdx.x & 31, ty = threadIdx.x >> 5;
    #pragma unroll
    for (int r = ty; r < 32; r += 8)
        tile[r][tx] = W[(size_t)(k0 + r) * N + n0 + tx];
    __syncthreads();
    #pragma unroll
    for (int r = ty; r < 32; r += 8)
        Wt[(size_t)(n0 + r) * K + k0 + tx] = f2bf(tile[tx][r]);
}

// ---------------- bf16 GEMM: C = A(MxK) * Bt(NxK)^T + bias ----------------
template<int MODE>
__global__ __launch_bounds__(256) void k_gemm(
    const u16* __restrict__ A, const u16* __restrict__ Bt,
    const float* __restrict__ bias,
    u16* __restrict__ q_out, u16* __restrict__ k_out, u16* __restrict__ vt_out,
    float* __restrict__ f_out,
    int N, int K)
{
    __shared__ u16 As[128 * 32];
    __shared__ u16 Bs[128 * 32];
    const int m0 = blockIdx.y * 128, n0 = blockIdx.x * 128;
    const int tid = threadIdx.x;
    const int w = tid >> 6, l = tid & 63;
    const int lr = l >> 2, lc = (l & 3) * 8;
    const int fr = l & 15, fk = (l >> 4) * 8;
    const int wm = (w >> 1) * 64, wn = (w & 1) * 64;
    f4_t acc[4][4] = {};

    for (int kt = 0; kt < K; kt += 32) {
        #pragma unroll
        for (int cc = 0; cc < 2; ++cc) {
            const int c = w + cc * 4;
            async_copy16(As + c * 512, A  + (size_t)(m0 + c * 16 + lr) * K + kt + lc);
            async_copy16(Bs + c * 512, Bt + (size_t)(n0 + c * 16 + lr) * K + kt + lc);
        }
        __syncthreads();
        bf8_t af[4], bfr[4];
        #pragma unroll
        for (int mf = 0; mf < 4; ++mf)
            af[mf] = *(const bf8_t*)&As[(wm + mf * 16 + fr) * 32 + fk];
        #pragma unroll
        for (int nf = 0; nf < 4; ++nf)
            bfr[nf] = *(const bf8_t*)&Bs[(wn + nf * 16 + fr) * 32 + fk];
        #pragma unroll
        for (int mf = 0; mf < 4; ++mf)
            #pragma unroll
            for (int nf = 0; nf < 4; ++nf)
                acc[mf][nf] = MFMA32(af[mf], bfr[nf], acc[mf][nf]);
        __syncthreads();
    }

    #pragma unroll
    for (int mf = 0; mf < 4; ++mf)
      #pragma unroll
      for (int nf = 0; nf < 4; ++nf)
        #pragma unroll
        for (int j = 0; j < 4; ++j) {
            const int m = m0 + wm + mf * 16 + (l >> 4) * 4 + j;
            const int n = n0 + wn + nf * 16 + (l & 15);
            float v = acc[mf][nf][j] + bias[n];
            if (MODE == 0) {
                const int h = n / 192, rem = n - h * 192;
                const int which = rem >> 6, dd = rem & 63;
                const int b = m >> 11, s = m & (SS - 1);
                const u16 bv = f2bf(v);
                const size_t qk_idx = ((size_t)(b * NHEADS + h) * SS + s) * DKH + dd;
                if (which == 0)      q_out[qk_idx] = bv;
                else if (which == 1) k_out[qk_idx] = bv;
                else                 vt_out[((size_t)(b * NHEADS + h) * DKH + dd) * SS + s] = bv;
            } else {
                f_out[(size_t)m * N + n] = v;
            }
        }
}

// ---------------- flash attention (swapped QK^T, P stays in registers) ----
// Block: 4 waves x 16 q-rows. Grid (32 bh, SS/64). KVBLK=64.
// LDS tiles [row][8 slots of 16B], slot XOR-swizzled by (row&7).
// QK^T computed as S^T = K*Q^T: lane (fr,fq) holds S[key=nf*16+fq*4+j][qrow=fr].
// PV uses a permuted key ordering pi(fq*8+e) = (2t+(e>>2))*16 + fq*4 + (e&3)
// applied to BOTH operands (bijective => exact): A-frag = packed P regs,
// B-frag = two ds_read_b64 from Vs per (t,df).
#define SCL 0.180336880f   // (1/8) * log2(e)

__global__ __launch_bounds__(256) void k_attn(
    const u16* __restrict__ Qg, const u16* __restrict__ Kg, const u16* __restrict__ Vtg,
    u16* __restrict__ ctx)
{
    __shared__ u16 Ks[64 * 64];        // [key][dk], swizzled
    __shared__ u16 Vs[64 * 64];        // [dk][key], swizzled
    const int bh = blockIdx.x;
    const int qt = blockIdx.y;
    const int tid = threadIdx.x, w = tid >> 6, l = tid & 63;
    const int fr = l & 15, fq = l >> 4;
    const int q0 = qt * 64 + w * 16;
    const u16* Qb = Qg  + (size_t)bh * SS * DKH;
    const u16* Kb = Kg  + (size_t)bh * SS * DKH;
    const u16* Vb = Vtg + (size_t)bh * DKH * SS;

    bf8_t qf[2];   // B-frag: col=qrow=fr, k = kh*32 + fq*8 + 0..7
    #pragma unroll
    for (int kh = 0; kh < 2; ++kh)
        qf[kh] = *(const bf8_t*)(Qb + (size_t)(q0 + fr) * DKH + kh * 32 + fq * 8);

    float mrow = -__builtin_inff(), lrow = 0.f;   // per-lane scalars (qrow = fr)
    f4_t o[4] = {};                                // O[qrow=fq*4+j][d=df*16+fr]

    for (int kv = 0; kv < SS; kv += 64) {
        #pragma unroll
        for (int it = 0; it < 2; ++it) {
            const int c = tid + it * 256;
            const int r = c >> 3, sl = c & 7;
            const int dsl = sl ^ (r & 7);
            *(uint4*)&Ks[r * 64 + dsl * 8] = *(const uint4*)(Kb + (size_t)(kv + r) * DKH + sl * 8);
            *(uint4*)&Vs[r * 64 + dsl * 8] = *(const uint4*)(Vb + (size_t)r * SS + kv + sl * 8);
        }
        __syncthreads();

        // S^T = K * Q^T : sa[nf][j] = S[key = nf*16+fq*4+j][qrow = fr]
        f4_t sa[4] = {};
        #pragma unroll
        for (int nf = 0; nf < 4; ++nf)
          #pragma unroll
          for (int kh = 0; kh < 2; ++kh) {
            const int row = nf * 16 + fr;            // key as A-frag row
            const int dsl = (kh * 4 + fq) ^ (fr & 7);
            const bf8_t kb = *(const bf8_t*)&Ks[row * 64 + dsl * 8];
            sa[nf] = MFMA32(kb, qf[kh], sa[nf]);
          }

        // per-lane softmax over this lane's q-row (16 in-lane values + 2 shfl)
        float x = sa[0][0];
        #pragma unroll
        for (int nf = 0; nf < 4; ++nf)
          #pragma unroll
          for (int j = 0; j < 4; ++j)
            x = fmaxf(x, sa[nf][j]);
        x *= SCL;
        x = fmaxf(x, __shfl_xor(x, 16));
        x = fmaxf(x, __shfl_xor(x, 32));

        if (__any(x > mrow + 8.f)) {               // defer-max (T13)
            float mnew = fmaxf(mrow, x);
            float sc = fexp2(mrow - mnew);
            lrow *= sc;
            mrow = mnew;
            float sc4[4];
            #pragma unroll
            for (int j = 0; j < 4; ++j) sc4[j] = __shfl(sc, fq * 4 + j);
            #pragma unroll
            for (int df = 0; df < 4; ++df)
              #pragma unroll
              for (int j = 0; j < 4; ++j)
                o[df][j] *= sc4[j];
        }

        float ps = 0.f;
        u32 pk[8];   // pk[nf*2+h] = bf16 pair (keys nf*16+fq*4+{2h,2h+1})
        #pragma unroll
        for (int nf = 0; nf < 4; ++nf) {
            float p0 = fexp2(sa[nf][0] * SCL - mrow);
            float p1 = fexp2(sa[nf][1] * SCL - mrow);
            float p2 = fexp2(sa[nf][2] * SCL - mrow);
            float p3 = fexp2(sa[nf][3] * SCL - mrow);
            ps += (p0 + p1) + (p2 + p3);
            pk[nf * 2 + 0] = ((u32)f2bf(p1) << 16) | f2bf(p0);
            pk[nf * 2 + 1] = ((u32)f2bf(p3) << 16) | f2bf(p2);
        }
        ps += __shfl_xor(ps, 16);
        ps += __shfl_xor(ps, 32);
        lrow += ps;

        // O += P V  (permuted-K MFMAs, P direct from registers)
        union { bf8_t v; u32 u[4]; } pa[2];
        #pragma unroll
        for (int t = 0; t < 2; ++t) {
            pa[t].u[0] = pk[4 * t + 0]; pa[t].u[1] = pk[4 * t + 1];
            pa[t].u[2] = pk[4 * t + 2]; pa[t].u[3] = pk[4 * t + 3];
        }
        #pragma unroll
        for (int t = 0; t < 2; ++t) {
            const int dslA = ((4 * t)     + (fq >> 1)) ^ (fr & 7);
            const int dslB = ((4 * t + 2) + (fq >> 1)) ^ (fr & 7);
            const int hoff = (fq & 1) * 4;
            #pragma unroll
            for (int df = 0; df < 4; ++df) {
                const int row = df * 16 + fr;
                union { bf8_t v; uint2 u[2]; } vv;
                vv.u[0] = *(const uint2*)&Vs[row * 64 + dslA * 8 + hoff];
                vv.u[1] = *(const uint2*)&Vs[row * 64 + dslB * 8 + hoff];
                o[df] = MFMA32(pa[t].v, vv.v, o[df]);
            }
        }
        __syncthreads();
    }

    // redistribute l (held at qrow=fr) to O's layout (qrow=fq*4+j)
    float ml[4];
    #pragma unroll
    for (int j = 0; j < 4; ++j) ml[j] = __shfl(lrow, fq * 4 + j);

    const int b = bh >> 4, h = bh & 15;
    #pragma unroll
    for (int df = 0; df < 4; ++df)
      #pragma unroll
      for (int j = 0; j < 4; ++j) {
        const int s = q0 + fq * 4 + j;
        const int dd = df * 16 + fr;
        float v = o[df][j] / ml[j];
        ctx[((size_t)(b * SS + s)) * DM + h * DKH + dd] = f2bf(v);
      }
}

// ---------------- launcher ----------------
extern "C" void kernel_launch(void* const* d_in, const int* in_sizes, int n_in,
                              void* d_out, int out_size, void* d_ws, size_t ws_size,
                              hipStream_t stream)
{
    const float* x     = (const float*)d_in[0];
    const float* W_qkv = (const float*)d_in[1];
    const float* b_qkv = (const float*)d_in[2];
    const float* W_o   = (const float*)d_in[3];
    const float* b_o   = (const float*)d_in[4];
    float* out = (float*)d_out;

    char* ws = (char*)d_ws;
    u16* xb   = (u16*)(ws);                                   // 4096x1024  (8 MB)
    u16* Wqkt = (u16*)(ws + 8388608);                         // 3072x1024  (6 MB)
    u16* Wot  = (u16*)(ws + 8388608 + 6291456);               // 1024x1024  (2 MB)
    u16* Qg   = (u16*)(ws + 16777216);                        // 32x2048x64 (8 MB)
    u16* Kg   = Qg  + 4194304;
    u16* Vtg  = Kg  + 4194304;
    u16* ctx  = xb;                                           // alias: xb dead after k_gemm<0>

    k_cvt<<<1024, 256, 0, stream>>>(x, xb, (MROWS * DM) / 4);
    k_transpose<<<dim3(3 * DM / 32, DM / 32), 256, 0, stream>>>(W_qkv, Wqkt, DM, 3 * DM);
    k_transpose<<<dim3(DM / 32, DM / 32), 256, 0, stream>>>(W_o, Wot, DM, DM);
    k_gemm<0><<<dim3(3 * DM / 128, MROWS / 128), 256, 0, stream>>>(
        xb, Wqkt, b_qkv, Qg, Kg, Vtg, nullptr, 3 * DM, DM);
    k_attn<<<dim3(BB * NHEADS, SS / 64), 256, 0, stream>>>(Qg, Kg, Vtg, ctx);
    k_gemm<1><<<dim3(DM / 128, MROWS / 128), 256, 0, stream>>>(
        ctx, Wot, b_o, nullptr, nullptr, nullptr, out, DM, DM);
}

// Round 5
// 226.697 us; speedup vs baseline: 1.3012x; 1.0150x over previous
//
#include <hip/hip_runtime.h>
#include <hip/hip_bf16.h>
#include <stdint.h>

#define NHEADS 16
#define DKH    64
#define BB     2
#define SS     2048
#define DM     1024
#define MROWS  (BB * SS)   // 4096

typedef __attribute__((ext_vector_type(8))) short bf8_t;   // 8 bf16 in 4 VGPRs
typedef __attribute__((ext_vector_type(4))) float f4_t;    // MFMA accum
typedef unsigned short u16;
typedef uint32_t u32;

__device__ __forceinline__ u16 f2bf(float f) {
    union { float f; u32 u; } v; v.f = f;
    return (u16)((v.u + 0x7fffu + ((v.u >> 16) & 1u)) >> 16);  // RNE
}

__device__ __forceinline__ u32 cvt_pk_bf16(float lo, float hi) {
    u32 r;
    asm("v_cvt_pk_bf16_f32 %0, %1, %2" : "=v"(r) : "v"(lo), "v"(hi));
    return r;
}

__device__ __forceinline__ float fexp2(float x) {
#if __has_builtin(__builtin_amdgcn_exp2f)
    return __builtin_amdgcn_exp2f(x);
#else
    return __expf(x * 0.69314718056f);
#endif
}

__device__ __forceinline__ void async_copy16(void* lds, const void* g) {
    __builtin_amdgcn_global_load_lds(
        (__attribute__((address_space(1))) void*)(void*)g,
        (__attribute__((address_space(3))) void*)lds, 16, 0, 0);
}

#define MFMA32(a, b, c) __builtin_amdgcn_mfma_f32_16x16x32_bf16(a, b, c, 0, 0, 0)

// ---------------- f32 -> bf16 elementwise ----------------
__global__ void k_cvt(const float* __restrict__ in, u16* __restrict__ out, int n4) {
    int stride = gridDim.x * blockDim.x;
    for (int i = blockIdx.x * blockDim.x + threadIdx.x; i < n4; i += stride) {
        float4 v = ((const float4*)in)[i];
        ushort4 o;
        o.x = f2bf(v.x); o.y = f2bf(v.y); o.z = f2bf(v.z); o.w = f2bf(v.w);
        ((ushort4*)out)[i] = o;
    }
}

// ---------------- W (K x N f32) -> Wt (N x K bf16) ----------------
__global__ void k_transpose(const float* __restrict__ W, u16* __restrict__ Wt, int K, int N) {
    __shared__ float tile[32][33];
    int n0 = blockIdx.x * 32, k0 = blockIdx.y * 32;
    int tx = threadIdx.x & 31, ty = threadIdx.x >> 5;
    #pragma unroll
    for (int r = ty; r < 32; r += 8)
        tile[r][tx] = W[(size_t)(k0 + r) * N + n0 + tx];
    __syncthreads();
    #pragma unroll
    for (int r = ty; r < 32; r += 8)
        Wt[(size_t)(n0 + r) * K + k0 + tx] = f2bf(tile[tx][r]);
}

// ---------------- bf16 GEMM: C = A(MxK) * Bt(NxK)^T + bias ----------------
template<int MODE>
__global__ __launch_bounds__(256) void k_gemm(
    const u16* __restrict__ A, const u16* __restrict__ Bt,
    const float* __restrict__ bias,
    u16* __restrict__ q_out, u16* __restrict__ k_out, u16* __restrict__ vt_out,
    float* __restrict__ f_out,
    int N, int K)
{
    __shared__ u16 As[128 * 32];
    __shared__ u16 Bs[128 * 32];
    const int m0 = blockIdx.y * 128, n0 = blockIdx.x * 128;
    const int tid = threadIdx.x;
    const int w = tid >> 6, l = tid & 63;
    const int lr = l >> 2, lc = (l & 3) * 8;
    const int fr = l & 15, fk = (l >> 4) * 8;
    const int wm = (w >> 1) * 64, wn = (w & 1) * 64;
    f4_t acc[4][4] = {};

    for (int kt = 0; kt < K; kt += 32) {
        #pragma unroll
        for (int cc = 0; cc < 2; ++cc) {
            const int c = w + cc * 4;
            async_copy16(As + c * 512, A  + (size_t)(m0 + c * 16 + lr) * K + kt + lc);
            async_copy16(Bs + c * 512, Bt + (size_t)(n0 + c * 16 + lr) * K + kt + lc);
        }
        __syncthreads();
        bf8_t af[4], bfr[4];
        #pragma unroll
        for (int mf = 0; mf < 4; ++mf)
            af[mf] = *(const bf8_t*)&As[(wm + mf * 16 + fr) * 32 + fk];
        #pragma unroll
        for (int nf = 0; nf < 4; ++nf)
            bfr[nf] = *(const bf8_t*)&Bs[(wn + nf * 16 + fr) * 32 + fk];
        #pragma unroll
        for (int mf = 0; mf < 4; ++mf)
            #pragma unroll
            for (int nf = 0; nf < 4; ++nf)
                acc[mf][nf] = MFMA32(af[mf], bfr[nf], acc[mf][nf]);
        __syncthreads();
    }

    #pragma unroll
    for (int mf = 0; mf < 4; ++mf)
      #pragma unroll
      for (int nf = 0; nf < 4; ++nf)
        #pragma unroll
        for (int j = 0; j < 4; ++j) {
            const int m = m0 + wm + mf * 16 + (l >> 4) * 4 + j;
            const int n = n0 + wn + nf * 16 + (l & 15);
            float v = acc[mf][nf][j] + bias[n];
            if (MODE == 0) {
                const int h = n / 192, rem = n - h * 192;
                const int which = rem >> 6, dd = rem & 63;
                const int b = m >> 11, s = m & (SS - 1);
                const u16 bv = f2bf(v);
                const size_t qk_idx = ((size_t)(b * NHEADS + h) * SS + s) * DKH + dd;
                if (which == 0)      q_out[qk_idx] = bv;
                else if (which == 1) k_out[qk_idx] = bv;
                else                 vt_out[((size_t)(b * NHEADS + h) * DKH + dd) * SS + s] = bv;
            } else {
                f_out[(size_t)m * N + n] = v;
            }
        }
}

// ---------------- flash attention (swapped QK^T, P in registers) ----------
// Block: 4 waves x 16 q-rows. Grid (32 bh, SS/64). KVBLK=64.
// LDS tiles [row][8 slots of 16B], slot XOR-swizzled by (row&7).
// K is staged with the sigma permutation (swap 2-bit fields of key index):
// staged row nf*16+fq*4+j holds physical key fq*16+nf*4+j, so each lane's
// P covers 16 consecutive physical keys -> PV B-frag is ONE b128 read.
#define SCL 0.180336880f   // (1/8) * log2(e)

__global__ __launch_bounds__(256) void k_attn(
    const u16* __restrict__ Qg, const u16* __restrict__ Kg, const u16* __restrict__ Vtg,
    u16* __restrict__ ctx)
{
    __shared__ u16 Ks[64 * 64];        // [staged key][dk], swizzled
    __shared__ u16 Vs[64 * 64];        // [dk][physical key], swizzled
    const int bh = blockIdx.x;
    const int qt = blockIdx.y;
    const int tid = threadIdx.x, w = tid >> 6, l = tid & 63;
    const int fr = l & 15, fq = l >> 4;
    const int q0 = qt * 64 + w * 16;
    const u16* Qb = Qg  + (size_t)bh * SS * DKH;
    const u16* Kb = Kg  + (size_t)bh * SS * DKH;
    const u16* Vb = Vtg + (size_t)bh * DKH * SS;

    bf8_t qf[2];   // B-frag: col=qrow=fr, k = kh*32 + fq*8 + 0..7
    #pragma unroll
    for (int kh = 0; kh < 2; ++kh)
        qf[kh] = *(const bf8_t*)(Qb + (size_t)(q0 + fr) * DKH + kh * 32 + fq * 8);

    float mrow = -__builtin_inff(), lrow = 0.f;   // per-lane scalars (qrow = fr)
    f4_t o[4] = {};                                // O[qrow=fq*4+j][d=df*16+fr]

    // per-lane staging indices (c = it*256 + tid)
    for (int kv = 0; kv < SS; kv += 64) {
        #pragma unroll
        for (int it = 0; it < 2; ++it) {
            const int c = tid + it * 256;
            const int r = c >> 3, dslw = c & 7;
            const int sl = dslw ^ (r & 7);                         // source 16B slot
            const int sr = ((r >> 2) & 3) * 16 + (r >> 4) * 4 + (r & 3);  // sigma(r)
            const int cb = it * 256 + w * 64;                      // wave-uniform chunk base
            async_copy16(Ks + cb * 8, Kb + (size_t)(kv + sr) * DKH + sl * 8);
            async_copy16(Vs + cb * 8, Vb + (size_t)r * SS + kv + sl * 8);
        }
        __syncthreads();

        // S^T = K * Q^T : sa[nf][j] = S[physkey = fq*16+nf*4+j][qrow = fr]
        f4_t sa[4] = {};
        #pragma unroll
        for (int nf = 0; nf < 4; ++nf)
          #pragma unroll
          for (int kh = 0; kh < 2; ++kh) {
            const int row = nf * 16 + fr;            // staged key as A-frag row
            const int dsl = (kh * 4 + fq) ^ (fr & 7);
            const bf8_t kb = *(const bf8_t*)&Ks[row * 64 + dsl * 8];
            sa[nf] = MFMA32(kb, qf[kh], sa[nf]);
          }

        // per-lane softmax over this lane's q-row (15 in-lane max + 2 shfl)
        float x = sa[0][0];
        #pragma unroll
        for (int nf = 0; nf < 4; ++nf)
          #pragma unroll
          for (int j = 0; j < 4; ++j)
            x = fmaxf(x, sa[nf][j]);
        x *= SCL;
        x = fmaxf(x, __shfl_xor(x, 16));
        x = fmaxf(x, __shfl_xor(x, 32));

        if (__any(x > mrow + 8.f)) {               // defer-max (T13)
            float mnew = fmaxf(mrow, x);
            float sc = fexp2(mrow - mnew);
            lrow *= sc;
            mrow = mnew;
            float sc4[4];
            #pragma unroll
            for (int j = 0; j < 4; ++j) sc4[j] = __shfl(sc, fq * 4 + j);
            #pragma unroll
            for (int df = 0; df < 4; ++df)
              #pragma unroll
              for (int j = 0; j < 4; ++j)
                o[df][j] *= sc4[j];
        }

        float ps = 0.f;
        u32 pk[8];   // pk[nf*2+h] = bf16 pair (physkeys fq*16+nf*4+{2h,2h+1})
        #pragma unroll
        for (int nf = 0; nf < 4; ++nf) {
            float p0 = fexp2(sa[nf][0] * SCL - mrow);
            float p1 = fexp2(sa[nf][1] * SCL - mrow);
            float p2 = fexp2(sa[nf][2] * SCL - mrow);
            float p3 = fexp2(sa[nf][3] * SCL - mrow);
            ps += (p0 + p1) + (p2 + p3);
            pk[nf * 2 + 0] = cvt_pk_bf16(p0, p1);
            pk[nf * 2 + 1] = cvt_pk_bf16(p2, p3);
        }
        ps += __shfl_xor(ps, 16);
        ps += __shfl_xor(ps, 32);
        lrow += ps;

        // O += P V : A-frag kslot fq*8+e -> physkey fq*16+t*8+e (in-lane),
        // B-frag = ONE b128 from Vs (8 consecutive physkeys at key0=fq*16+t*8)
        union { bf8_t v; u32 u[4]; } pa[2];
        #pragma unroll
        for (int t = 0; t < 2; ++t) {
            pa[t].u[0] = pk[4 * t + 0]; pa[t].u[1] = pk[4 * t + 1];
            pa[t].u[2] = pk[4 * t + 2]; pa[t].u[3] = pk[4 * t + 3];
        }
        #pragma unroll
        for (int t = 0; t < 2; ++t) {
            const int dsl = (fq * 2 + t) ^ (fr & 7);
            #pragma unroll
            for (int df = 0; df < 4; ++df) {
                const bf8_t vv = *(const bf8_t*)&Vs[(df * 16 + fr) * 64 + dsl * 8];
                o[df] = MFMA32(pa[t].v, vv, o[df]);
            }
        }
        __syncthreads();
    }

    // redistribute l (held at qrow=fr) to O's layout (qrow=fq*4+j)
    float ml[4];
    #pragma unroll
    for (int j = 0; j < 4; ++j) ml[j] = __shfl(lrow, fq * 4 + j);

    const int b = bh >> 4, h = bh & 15;
    #pragma unroll
    for (int df = 0; df < 4; ++df)
      #pragma unroll
      for (int j = 0; j < 4; ++j) {
        const int s = q0 + fq * 4 + j;
        const int dd = df * 16 + fr;
        float v = o[df][j] / ml[j];
        ctx[((size_t)(b * SS + s)) * DM + h * DKH + dd] = f2bf(v);
      }
}

// ---------------- launcher ----------------
extern "C" void kernel_launch(void* const* d_in, const int* in_sizes, int n_in,
                              void* d_out, int out_size, void* d_ws, size_t ws_size,
                              hipStream_t stream)
{
    const float* x     = (const float*)d_in[0];
    const float* W_qkv = (const float*)d_in[1];
    const float* b_qkv = (const float*)d_in[2];
    const float* W_o   = (const float*)d_in[3];
    const float* b_o   = (const float*)d_in[4];
    float* out = (float*)d_out;

    char* ws = (char*)d_ws;
    u16* xb   = (u16*)(ws);                                   // 4096x1024  (8 MB)
    u16* Wqkt = (u16*)(ws + 8388608);                         // 3072x1024  (6 MB)
    u16* Wot  = (u16*)(ws + 8388608 + 6291456);               // 1024x1024  (2 MB)
    u16* Qg   = (u16*)(ws + 16777216);                        // 32x2048x64 (8 MB)
    u16* Kg   = Qg  + 4194304;
    u16* Vtg  = Kg  + 4194304;
    u16* ctx  = xb;                                           // alias: xb dead after k_gemm<0>

    k_cvt<<<1024, 256, 0, stream>>>(x, xb, (MROWS * DM) / 4);
    k_transpose<<<dim3(3 * DM / 32, DM / 32), 256, 0, stream>>>(W_qkv, Wqkt, DM, 3 * DM);
    k_transpose<<<dim3(DM / 32, DM / 32), 256, 0, stream>>>(W_o, Wot, DM, DM);
    k_gemm<0><<<dim3(3 * DM / 128, MROWS / 128), 256, 0, stream>>>(
        xb, Wqkt, b_qkv, Qg, Kg, Vtg, nullptr, 3 * DM, DM);
    k_attn<<<dim3(BB * NHEADS, SS / 64), 256, 0, stream>>>(Qg, Kg, Vtg, ctx);
    k_gemm<1><<<dim3(DM / 128, MROWS / 128), 256, 0, stream>>>(
        ctx, Wot, b_o, nullptr, nullptr, nullptr, out, DM, DM);
}

// Round 6
// 198.054 us; speedup vs baseline: 1.4893x; 1.1446x over previous
//
#include <hip/hip_runtime.h>
#include <hip/hip_bf16.h>
#include <stdint.h>

#define NHEADS 16
#define DKH    64
#define BB     2
#define SS     2048
#define DM     1024
#define MROWS  (BB * SS)   // 4096

typedef __attribute__((ext_vector_type(8))) short bf8_t;   // 8 bf16 in 4 VGPRs
typedef __attribute__((ext_vector_type(4))) float f4_t;    // MFMA accum
typedef unsigned short u16;
typedef uint32_t u32;

__device__ __forceinline__ u16 f2bf(float f) {
    union { float f; u32 u; } v; v.f = f;
    return (u16)((v.u + 0x7fffu + ((v.u >> 16) & 1u)) >> 16);  // RNE
}

__device__ __forceinline__ u32 cvt_pk_bf16(float lo, float hi) {
    u32 r;
    asm("v_cvt_pk_bf16_f32 %0, %1, %2" : "=v"(r) : "v"(lo), "v"(hi));
    return r;
}

__device__ __forceinline__ float fexp2(float x) {
#if __has_builtin(__builtin_amdgcn_exp2f)
    return __builtin_amdgcn_exp2f(x);
#else
    return __expf(x * 0.69314718056f);
#endif
}

__device__ __forceinline__ void async_copy16(void* lds, const void* g) {
    __builtin_amdgcn_global_load_lds(
        (__attribute__((address_space(1))) void*)(void*)g,
        (__attribute__((address_space(3))) void*)lds, 16, 0, 0);
}

#define MFMA32(a, b, c) __builtin_amdgcn_mfma_f32_16x16x32_bf16(a, b, c, 0, 0, 0)

// ---------------- f32 -> bf16 elementwise ----------------
__global__ void k_cvt(const float* __restrict__ in, u16* __restrict__ out, int n4) {
    int stride = gridDim.x * blockDim.x;
    for (int i = blockIdx.x * blockDim.x + threadIdx.x; i < n4; i += stride) {
        float4 v = ((const float4*)in)[i];
        ushort4 o;
        o.x = f2bf(v.x); o.y = f2bf(v.y); o.z = f2bf(v.z); o.w = f2bf(v.w);
        ((ushort4*)out)[i] = o;
    }
}

// ---------------- W (K x N f32) -> Wt (N x K bf16) ----------------
__global__ void k_transpose(const float* __restrict__ W, u16* __restrict__ Wt, int K, int N) {
    __shared__ float tile[32][33];
    int n0 = blockIdx.x * 32, k0 = blockIdx.y * 32;
    int tx = threadIdx.x & 31, ty = threadIdx.x >> 5;
    #pragma unroll
    for (int r = ty; r < 32; r += 8)
        tile[r][tx] = W[(size_t)(k0 + r) * N + n0 + tx];
    __syncthreads();
    #pragma unroll
    for (int r = ty; r < 32; r += 8)
        Wt[(size_t)(n0 + r) * K + k0 + tx] = f2bf(tile[tx][r]);
}

// ---------------- V[b,h,s,dk] -> Vt[b,h,dk,s] (coalesced both sides) ------
__global__ __launch_bounds__(256) void k_vt(const u16* __restrict__ V, u16* __restrict__ Vt) {
    __shared__ u16 t[64][72];          // +8 pad: rows offset by 4 banks
    const int bh = blockIdx.y;
    const int s0 = blockIdx.x * 64;
    const u16* Vb = V + (size_t)bh * SS * DKH;
    u16* Tb = Vt + (size_t)bh * DKH * SS;
    const int tid = threadIdx.x;
    #pragma unroll
    for (int it = 0; it < 2; ++it) {
        const int c = tid + it * 256;
        const int r = c >> 3, sl = c & 7;
        *(uint4*)&t[r][sl * 8] = *(const uint4*)(Vb + (size_t)(s0 + r) * DKH + sl * 8);
    }
    __syncthreads();
    #pragma unroll
    for (int it = 0; it < 2; ++it) {
        const int c = tid + it * 256;
        const int d = c >> 3, sl = c & 7;
        uint4 o;
        o.x = t[sl * 8 + 0][d] | ((u32)t[sl * 8 + 1][d] << 16);
        o.y = t[sl * 8 + 2][d] | ((u32)t[sl * 8 + 3][d] << 16);
        o.z = t[sl * 8 + 4][d] | ((u32)t[sl * 8 + 5][d] << 16);
        o.w = t[sl * 8 + 6][d] | ((u32)t[sl * 8 + 7][d] << 16);
        *(uint4*)(Tb + (size_t)d * SS + s0 + sl * 8) = o;
    }
}

// ---------------- bf16 GEMM: C = A(MxK) * Bt(NxK)^T + bias ----------------
// Tile BMT x BNT, 4 waves in 2x2. MODE 0: scatter epilogue to Q/K/V
// [b,h,s,dk] (all linear). MODE 1: fp32 C row-major.
template<int MODE, int BMT, int BNT>
__global__ __launch_bounds__(256) void k_gemm(
    const u16* __restrict__ A, const u16* __restrict__ Bt,
    const float* __restrict__ bias,
    u16* __restrict__ q_out, u16* __restrict__ k_out, u16* __restrict__ v_out,
    float* __restrict__ f_out,
    int N, int K)
{
    constexpr int MF = BMT / 32, NF = BNT / 32;   // per-wave fragment counts
    __shared__ u16 As[BMT * 32];
    __shared__ u16 Bs[BNT * 32];
    const int m0 = blockIdx.y * BMT, n0 = blockIdx.x * BNT;
    const int tid = threadIdx.x;
    const int w = tid >> 6, l = tid & 63;
    const int lr = l >> 2, lc = (l & 3) * 8;
    const int fr = l & 15, fk = (l >> 4) * 8;
    const int wm = (w >> 1) * (BMT / 2), wn = (w & 1) * (BNT / 2);
    f4_t acc[MF][NF] = {};

    for (int kt = 0; kt < K; kt += 32) {
        #pragma unroll
        for (int c = w; c < BMT / 16; c += 4)
            async_copy16(As + c * 512, A  + (size_t)(m0 + c * 16 + lr) * K + kt + lc);
        #pragma unroll
        for (int c = w; c < BNT / 16; c += 4)
            async_copy16(Bs + c * 512, Bt + (size_t)(n0 + c * 16 + lr) * K + kt + lc);
        __syncthreads();
        bf8_t af[MF], bfr[NF];
        #pragma unroll
        for (int mf = 0; mf < MF; ++mf)
            af[mf] = *(const bf8_t*)&As[(wm + mf * 16 + fr) * 32 + fk];
        #pragma unroll
        for (int nf = 0; nf < NF; ++nf)
            bfr[nf] = *(const bf8_t*)&Bs[(wn + nf * 16 + fr) * 32 + fk];
        #pragma unroll
        for (int mf = 0; mf < MF; ++mf)
            #pragma unroll
            for (int nf = 0; nf < NF; ++nf)
                acc[mf][nf] = MFMA32(af[mf], bfr[nf], acc[mf][nf]);
        __syncthreads();
    }

    #pragma unroll
    for (int mf = 0; mf < MF; ++mf)
      #pragma unroll
      for (int nf = 0; nf < NF; ++nf)
        #pragma unroll
        for (int j = 0; j < 4; ++j) {
            const int m = m0 + wm + mf * 16 + (l >> 4) * 4 + j;
            const int n = n0 + wn + nf * 16 + (l & 15);
            float v = acc[mf][nf][j] + bias[n];
            if (MODE == 0) {
                const int h = n / 192, rem = n - h * 192;
                const int which = rem >> 6, dd = rem & 63;
                const int b = m >> 11, s = m & (SS - 1);
                const size_t idx = ((size_t)(b * NHEADS + h) * SS + s) * DKH + dd;
                u16* dst = (which == 0) ? q_out : ((which == 1) ? k_out : v_out);
                dst[idx] = f2bf(v);
            } else {
                f_out[(size_t)m * N + n] = v;
            }
        }
}

// ---------------- flash attention (swapped QK^T, P in registers) ----------
// Block: 4 waves x 16 q-rows. Grid (32 bh, SS/64). KVBLK=128.
// K staged with sigma: staged row nf*16+fq*4+j <-> physical key fq*32+nf*4+j
// so each lane's P covers 32 consecutive physical keys; PV B-frag = 1 b128.
// LDS 16B slots XOR-swizzled by (row&7) on the low 3 slot bits.
#define SCL 0.180336880f   // (1/8) * log2(e)

__global__ __launch_bounds__(256, 4) void k_attn(
    const u16* __restrict__ Qg, const u16* __restrict__ Kg, const u16* __restrict__ Vtg,
    u16* __restrict__ ctx)
{
    __shared__ u16 Ks[128 * 64];       // [staged key][dk]
    __shared__ u16 Vs[64 * 128];       // [dk][physical key]
    const int bh = blockIdx.x;
    const int qt = blockIdx.y;
    const int tid = threadIdx.x, w = tid >> 6, l = tid & 63;
    const int fr = l & 15, fq = l >> 4;
    const int q0 = qt * 64 + w * 16;
    const u16* Qb = Qg  + (size_t)bh * SS * DKH;
    const u16* Kb = Kg  + (size_t)bh * SS * DKH;
    const u16* Vb = Vtg + (size_t)bh * DKH * SS;

    bf8_t qf[2];   // B-frag: col=qrow=fr, k = kh*32 + fq*8 + 0..7
    #pragma unroll
    for (int kh = 0; kh < 2; ++kh)
        qf[kh] = *(const bf8_t*)(Qb + (size_t)(q0 + fr) * DKH + kh * 32 + fq * 8);

    float mrow = -__builtin_inff(), lrow = 0.f;   // per-lane scalars (qrow = fr)
    f4_t o[4] = {};                                // O[qrow=fq*4+j][d=df*16+fr]

    for (int kv = 0; kv < SS; kv += 128) {
        #pragma unroll
        for (int it = 0; it < 4; ++it) {
            const int c = tid + it * 256;
            const int cb = it * 256 + w * 64;                      // wave-uniform
            // K: 128 rows x 8 slots
            const int rk = c >> 3;
            const int slk = (c & 7) ^ (rk & 7);
            const int sr = ((rk >> 2) & 3) * 32 + (rk >> 4) * 4 + (rk & 3);  // sigma
            async_copy16(Ks + cb * 8, Kb + (size_t)(kv + sr) * DKH + slk * 8);
            // V: 64 rows x 16 slots
            const int rv = c >> 4;
            const int slv = (c & 15) ^ (rv & 7);
            async_copy16(Vs + cb * 8, Vb + (size_t)rv * SS + kv + slv * 8);
        }
        __syncthreads();

        // S^T = K * Q^T : sa[nf][j] = S[physkey = fq*32+nf*4+j][qrow = fr]
        f4_t sa[8] = {};
        #pragma unroll
        for (int nf = 0; nf < 8; ++nf)
          #pragma unroll
          for (int kh = 0; kh < 2; ++kh) {
            const int row = nf * 16 + fr;
            const int dsl = (kh * 4 + fq) ^ (fr & 7);
            const bf8_t kb = *(const bf8_t*)&Ks[row * 64 + dsl * 8];
            sa[nf] = MFMA32(kb, qf[kh], sa[nf]);
          }

        // per-lane softmax over this lane's q-row (31 in-lane max + 2 shfl)
        float x = sa[0][0];
        #pragma unroll
        for (int nf = 0; nf < 8; ++nf)
          #pragma unroll
          for (int j = 0; j < 4; ++j)
            x = fmaxf(x, sa[nf][j]);
        x *= SCL;
        x = fmaxf(x, __shfl_xor(x, 16));
        x = fmaxf(x, __shfl_xor(x, 32));

        if (__any(x > mrow + 8.f)) {               // defer-max (T13)
            float mnew = fmaxf(mrow, x);
            float sc = fexp2(mrow - mnew);
            lrow *= sc;
            mrow = mnew;
            float sc4[4];
            #pragma unroll
            for (int j = 0; j < 4; ++j) sc4[j] = __shfl(sc, fq * 4 + j);
            #pragma unroll
            for (int df = 0; df < 4; ++df)
              #pragma unroll
              for (int j = 0; j < 4; ++j)
                o[df][j] *= sc4[j];
        }

        float ps = 0.f;
        u32 pk[16];  // pk[nf*2+h] = bf16 pair (physkeys fq*32+nf*4+{2h,2h+1})
        #pragma unroll
        for (int nf = 0; nf < 8; ++nf) {
            float p0 = fexp2(sa[nf][0] * SCL - mrow);
            float p1 = fexp2(sa[nf][1] * SCL - mrow);
            float p2 = fexp2(sa[nf][2] * SCL - mrow);
            float p3 = fexp2(sa[nf][3] * SCL - mrow);
            ps += (p0 + p1) + (p2 + p3);
            pk[nf * 2 + 0] = cvt_pk_bf16(p0, p1);
            pk[nf * 2 + 1] = cvt_pk_bf16(p2, p3);
        }
        ps += __shfl_xor(ps, 16);
        ps += __shfl_xor(ps, 32);
        lrow += ps;

        // O += P V : pa[t] = physkeys [fq*32+8t, +8); B-frag = 1 b128 from Vs
        #pragma unroll
        for (int t = 0; t < 4; ++t) {
            union { bf8_t v; u32 u[4]; } pa;
            pa.u[0] = pk[4 * t + 0]; pa.u[1] = pk[4 * t + 1];
            pa.u[2] = pk[4 * t + 2]; pa.u[3] = pk[4 * t + 3];
            const int sl = fq * 4 + t;
            #pragma unroll
            for (int df = 0; df < 4; ++df) {
                const int rv = df * 16 + fr;
                const int dsl = sl ^ (rv & 7);
                const bf8_t vv = *(const bf8_t*)&Vs[rv * 128 + dsl * 8];
                o[df] = MFMA32(pa.v, vv, o[df]);
            }
        }
        __syncthreads();
    }

    // redistribute l (held at qrow=fr) to O's layout (qrow=fq*4+j)
    float ml[4];
    #pragma unroll
    for (int j = 0; j < 4; ++j) ml[j] = __shfl(lrow, fq * 4 + j);

    const int b = bh >> 4, h = bh & 15;
    #pragma unroll
    for (int df = 0; df < 4; ++df)
      #pragma unroll
      for (int j = 0; j < 4; ++j) {
        const int s = q0 + fq * 4 + j;
        const int dd = df * 16 + fr;
        float v = o[df][j] / ml[j];
        ctx[((size_t)(b * SS + s)) * DM + h * DKH + dd] = f2bf(v);
      }
}

// ---------------- launcher ----------------
extern "C" void kernel_launch(void* const* d_in, const int* in_sizes, int n_in,
                              void* d_out, int out_size, void* d_ws, size_t ws_size,
                              hipStream_t stream)
{
    const float* x     = (const float*)d_in[0];
    const float* W_qkv = (const float*)d_in[1];
    const float* b_qkv = (const float*)d_in[2];
    const float* W_o   = (const float*)d_in[3];
    const float* b_o   = (const float*)d_in[4];
    float* out = (float*)d_out;

    char* ws = (char*)d_ws;
    u16* xb   = (u16*)(ws);                                   // 4096x1024  (8 MB)
    u16* Wqkt = (u16*)(ws + 8388608);                         // 3072x1024  (6 MB)
    u16* Wot  = (u16*)(ws + 8388608 + 6291456);               // 1024x1024  (2 MB)
    u16* Qg   = (u16*)(ws + 16777216);                        // 32x2048x64 (8 MB)
    u16* Kg   = Qg  + 4194304;
    u16* Vg   = Kg  + 4194304;                                // V linear
    u16* Vtg  = Vg  + 4194304;                                // V transposed
    u16* ctx  = xb;                                           // alias: xb dead after k_gemm<0>

    k_cvt<<<1024, 256, 0, stream>>>(x, xb, (MROWS * DM) / 4);
    k_transpose<<<dim3(3 * DM / 32, DM / 32), 256, 0, stream>>>(W_qkv, Wqkt, DM, 3 * DM);
    k_transpose<<<dim3(DM / 32, DM / 32), 256, 0, stream>>>(W_o, Wot, DM, DM);
    k_gemm<0, 128, 128><<<dim3(3 * DM / 128, MROWS / 128), 256, 0, stream>>>(
        xb, Wqkt, b_qkv, Qg, Kg, Vg, nullptr, 3 * DM, DM);
    k_vt<<<dim3(SS / 64, BB * NHEADS), 256, 0, stream>>>(Vg, Vtg);
    k_attn<<<dim3(BB * NHEADS, SS / 64), 256, 0, stream>>>(Qg, Kg, Vtg, ctx);
    k_gemm<1, 64, 64><<<dim3(DM / 64, MROWS / 64), 256, 0, stream>>>(
        ctx, Wot, b_o, nullptr, nullptr, nullptr, out, DM, DM);
}

// Round 7
// 189.592 us; speedup vs baseline: 1.5558x; 1.0446x over previous
//
#include <hip/hip_runtime.h>
#include <hip/hip_bf16.h>
#include <stdint.h>

#define NHEADS 16
#define DKH    64
#define BB     2
#define SS     2048
#define DM     1024
#define MROWS  (BB * SS)   // 4096

typedef __attribute__((ext_vector_type(8))) short bf8_t;   // 8 bf16 in 4 VGPRs
typedef __attribute__((ext_vector_type(4))) float f4_t;    // MFMA accum
typedef unsigned short u16;
typedef uint32_t u32;

__device__ __forceinline__ u16 f2bf(float f) {
    union { float f; u32 u; } v; v.f = f;
    return (u16)((v.u + 0x7fffu + ((v.u >> 16) & 1u)) >> 16);  // RNE
}

__device__ __forceinline__ u32 cvt_pk_bf16(float lo, float hi) {
    u32 r;
    asm("v_cvt_pk_bf16_f32 %0, %1, %2" : "=v"(r) : "v"(lo), "v"(hi));
    return r;
}

__device__ __forceinline__ float fexp2(float x) {
#if __has_builtin(__builtin_amdgcn_exp2f)
    return __builtin_amdgcn_exp2f(x);
#else
    return __expf(x * 0.69314718056f);
#endif
}

__device__ __forceinline__ void async_copy16(void* lds, const void* g) {
    __builtin_amdgcn_global_load_lds(
        (__attribute__((address_space(1))) void*)(void*)g,
        (__attribute__((address_space(3))) void*)lds, 16, 0, 0);
}

#define MFMA32(a, b, c) __builtin_amdgcn_mfma_f32_16x16x32_bf16(a, b, c, 0, 0, 0)

// ---------------- prep: x->bf16, Wqkv^T, Wo^T in one launch ----------------
__global__ __launch_bounds__(256) void k_prep(
    const float* __restrict__ x, const float* __restrict__ Wqkv,
    const float* __restrict__ Wo,
    u16* __restrict__ xb, u16* __restrict__ Wqkt, u16* __restrict__ Wot)
{
    __shared__ float tile[32][33];
    const int blk = blockIdx.x;
    const int tx = threadIdx.x & 31, ty = threadIdx.x >> 5;
    if (blk < 3072) {          // Wqkv (DM x 3DM) -> Wqkt (3DM x DM)
        const int n0 = (blk % 96) * 32, k0 = (blk / 96) * 32;
        #pragma unroll
        for (int r = ty; r < 32; r += 8)
            tile[r][tx] = Wqkv[(size_t)(k0 + r) * (3 * DM) + n0 + tx];
        __syncthreads();
        #pragma unroll
        for (int r = ty; r < 32; r += 8)
            Wqkt[(size_t)(n0 + r) * DM + k0 + tx] = f2bf(tile[tx][r]);
    } else if (blk < 4096) {   // Wo (DM x DM) -> Wot (DM x DM)
        const int b2 = blk - 3072;
        const int n0 = (b2 % 32) * 32, k0 = (b2 / 32) * 32;
        #pragma unroll
        for (int r = ty; r < 32; r += 8)
            tile[r][tx] = Wo[(size_t)(k0 + r) * DM + n0 + tx];
        __syncthreads();
        #pragma unroll
        for (int r = ty; r < 32; r += 8)
            Wot[(size_t)(n0 + r) * DM + k0 + tx] = f2bf(tile[tx][r]);
    } else {                   // x f32 -> bf16, 512 blocks grid-stride
        const int b2 = blk - 4096;
        const int n4 = (MROWS * DM) / 4;
        for (int i = b2 * 256 + threadIdx.x; i < n4; i += 512 * 256) {
            float4 v = ((const float4*)x)[i];
            ushort4 o;
            o.x = f2bf(v.x); o.y = f2bf(v.y); o.z = f2bf(v.z); o.w = f2bf(v.w);
            ((ushort4*)xb)[i] = o;
        }
    }
}

// ---------------- V[b,h,s,dk] -> Vt[b,h,dk,s] ----------------
__global__ __launch_bounds__(256) void k_vt(const u16* __restrict__ V, u16* __restrict__ Vt) {
    __shared__ u16 t[64][72];
    const int bh = blockIdx.y;
    const int s0 = blockIdx.x * 64;
    const u16* Vb = V + (size_t)bh * SS * DKH;
    u16* Tb = Vt + (size_t)bh * DKH * SS;
    const int tid = threadIdx.x;
    #pragma unroll
    for (int it = 0; it < 2; ++it) {
        const int c = tid + it * 256;
        const int r = c >> 3, sl = c & 7;
        *(uint4*)&t[r][sl * 8] = *(const uint4*)(Vb + (size_t)(s0 + r) * DKH + sl * 8);
    }
    __syncthreads();
    #pragma unroll
    for (int it = 0; it < 2; ++it) {
        const int c = tid + it * 256;
        const int d = c >> 3, sl = c & 7;
        uint4 o;
        o.x = t[sl * 8 + 0][d] | ((u32)t[sl * 8 + 1][d] << 16);
        o.y = t[sl * 8 + 2][d] | ((u32)t[sl * 8 + 3][d] << 16);
        o.z = t[sl * 8 + 4][d] | ((u32)t[sl * 8 + 5][d] << 16);
        o.w = t[sl * 8 + 6][d] | ((u32)t[sl * 8 + 7][d] << 16);
        *(uint4*)(Tb + (size_t)d * SS + s0 + sl * 8) = o;
    }
}

// ---------------- bf16 GEMM, double-buffered prefetch ----------------
template<int MODE, int BMT, int BNT>
__global__ __launch_bounds__(256) void k_gemm(
    const u16* __restrict__ A, const u16* __restrict__ Bt,
    const float* __restrict__ bias,
    u16* __restrict__ q_out, u16* __restrict__ k_out, u16* __restrict__ v_out,
    float* __restrict__ f_out,
    int N, int K)
{
    constexpr int MF = BMT / 32, NF = BNT / 32;
    __shared__ u16 As[2][BMT * 32];
    __shared__ u16 Bs[2][BNT * 32];
    const int m0 = blockIdx.y * BMT, n0 = blockIdx.x * BNT;
    const int tid = threadIdx.x;
    const int w = tid >> 6, l = tid & 63;
    const int lr = l >> 2, lc = (l & 3) * 8;
    const int fr = l & 15, fk = (l >> 4) * 8;
    const int wm = (w >> 1) * (BMT / 2), wn = (w & 1) * (BNT / 2);
    f4_t acc[MF][NF] = {};

    auto stage = [&](int kt, int buf) {
        #pragma unroll
        for (int cc = 0; cc < BMT / 64; ++cc) {
            const int c = w + cc * 4;
            async_copy16(&As[buf][c * 512], A + (size_t)(m0 + c * 16 + lr) * K + kt + lc);
        }
        #pragma unroll
        for (int cc = 0; cc < BNT / 64; ++cc) {
            const int c = w + cc * 4;
            async_copy16(&Bs[buf][c * 512], Bt + (size_t)(n0 + c * 16 + lr) * K + kt + lc);
        }
    };

    stage(0, 0);
    __syncthreads();
    int cur = 0;
    for (int kt = 0; kt < K; kt += 32) {
        if (kt + 32 < K) stage(kt + 32, cur ^ 1);
        bf8_t af[MF], bfr[NF];
        #pragma unroll
        for (int mf = 0; mf < MF; ++mf)
            af[mf] = *(const bf8_t*)&As[cur][(wm + mf * 16 + fr) * 32 + fk];
        #pragma unroll
        for (int nf = 0; nf < NF; ++nf)
            bfr[nf] = *(const bf8_t*)&Bs[cur][(wn + nf * 16 + fr) * 32 + fk];
        #pragma unroll
        for (int mf = 0; mf < MF; ++mf)
            #pragma unroll
            for (int nf = 0; nf < NF; ++nf)
                acc[mf][nf] = MFMA32(af[mf], bfr[nf], acc[mf][nf]);
        __syncthreads();
        cur ^= 1;
    }

    #pragma unroll
    for (int mf = 0; mf < MF; ++mf)
      #pragma unroll
      for (int nf = 0; nf < NF; ++nf)
        #pragma unroll
        for (int j = 0; j < 4; ++j) {
            const int m = m0 + wm + mf * 16 + (l >> 4) * 4 + j;
            const int n = n0 + wn + nf * 16 + (l & 15);
            float v = acc[mf][nf][j] + bias[n];
            if (MODE == 0) {
                const int h = n / 192, rem = n - h * 192;
                const int which = rem >> 6, dd = rem & 63;
                const int b = m >> 11, s = m & (SS - 1);
                const size_t idx = ((size_t)(b * NHEADS + h) * SS + s) * DKH + dd;
                u16* dst = (which == 0) ? q_out : ((which == 1) ? k_out : v_out);
                dst[idx] = f2bf(v);
            } else {
                f_out[(size_t)m * N + n] = v;
            }
        }
}

// ---------------- flash attention ----------------
// Block: 4 waves x 32 q-rows = 128 q rows. Grid (32 bh, SS/128). KVBLK=128.
// Double-buffered K/V (64KB LDS), stage(t+1) issued before compute(t).
// Swapped QK^T per q-group mf: S^T = K*Q^T; sigma-permuted K staging so each
// lane's P covers 32 consecutive physical keys; PV B-frag = 1 b128, reused
// across both mf groups.
#define SCL 0.180336880f   // (1/8) * log2(e)

__global__ __launch_bounds__(256, 2) void k_attn(
    const u16* __restrict__ Qg, const u16* __restrict__ Kg, const u16* __restrict__ Vtg,
    u16* __restrict__ ctx)
{
    __shared__ u16 Ks[2][128 * 64];    // [staged key][dk]
    __shared__ u16 Vs[2][64 * 128];    // [dk][physical key]
    const int bh = blockIdx.x;
    const int qt = blockIdx.y;
    const int tid = threadIdx.x, w = tid >> 6, l = tid & 63;
    const int fr = l & 15, fq = l >> 4;
    const int q0 = qt * 128 + w * 32;
    const u16* Qb = Qg  + (size_t)bh * SS * DKH;
    const u16* Kb = Kg  + (size_t)bh * SS * DKH;
    const u16* Vb = Vtg + (size_t)bh * DKH * SS;

    bf8_t qf[2][2];   // [mf][kh]  B-frag: col=qrow, k = kh*32 + fq*8 + e
    #pragma unroll
    for (int mf = 0; mf < 2; ++mf)
      #pragma unroll
      for (int kh = 0; kh < 2; ++kh)
        qf[mf][kh] = *(const bf8_t*)(Qb + (size_t)(q0 + mf * 16 + fr) * DKH + kh * 32 + fq * 8);

    float mrow[2] = {-__builtin_inff(), -__builtin_inff()};
    float lrow[2] = {0.f, 0.f};
    f4_t o[2][4] = {};                 // O[mf][qrow=fq*4+j][d=df*16+fr]

    auto stage = [&](int kv, int buf) {
        #pragma unroll
        for (int it = 0; it < 4; ++it) {
            const int c = tid + it * 256;
            const int cb = it * 256 + w * 64;          // wave-uniform chunk base
            const int rk = c >> 3;
            const int slk = (c & 7) ^ (rk & 7);
            const int sr = ((rk >> 2) & 3) * 32 + (rk >> 4) * 4 + (rk & 3);  // sigma
            async_copy16(&Ks[buf][cb * 8], Kb + (size_t)(kv + sr) * DKH + slk * 8);
            const int rv = c >> 4;
            const int slv = (c & 15) ^ (rv & 7);
            async_copy16(&Vs[buf][cb * 8], Vb + (size_t)rv * SS + kv + slv * 8);
        }
    };

    stage(0, 0);
    __syncthreads();
    int cur = 0;
    for (int kv = 0; kv < SS; kv += 128) {
        if (kv + 128 < SS) stage(kv + 128, cur ^ 1);

        u32 pk[2][16];  // [mf][nf*2+h]: physkeys fq*32+nf*4+{2h,2h+1}
        #pragma unroll
        for (int mf = 0; mf < 2; ++mf) {
            // S^T = K * Q^T : sa[nf][j] = S[physkey = fq*32+nf*4+j][qrow]
            f4_t sa[8] = {};
            #pragma unroll
            for (int nf = 0; nf < 8; ++nf)
              #pragma unroll
              for (int kh = 0; kh < 2; ++kh) {
                const int row = nf * 16 + fr;
                const int dsl = (kh * 4 + fq) ^ (fr & 7);
                const bf8_t kb = *(const bf8_t*)&Ks[cur][row * 64 + dsl * 8];
                sa[nf] = MFMA32(kb, qf[mf][kh], sa[nf]);
              }

            float x = sa[0][0];
            #pragma unroll
            for (int nf = 0; nf < 8; ++nf)
              #pragma unroll
              for (int j = 0; j < 4; ++j)
                x = fmaxf(x, sa[nf][j]);
            x *= SCL;
            x = fmaxf(x, __shfl_xor(x, 16));
            x = fmaxf(x, __shfl_xor(x, 32));

            if (__any(x > mrow[mf] + 8.f)) {       // defer-max (T13)
                float mnew = fmaxf(mrow[mf], x);
                float sc = fexp2(mrow[mf] - mnew);
                lrow[mf] *= sc;
                mrow[mf] = mnew;
                float sc4[4];
                #pragma unroll
                for (int j = 0; j < 4; ++j) sc4[j] = __shfl(sc, fq * 4 + j);
                #pragma unroll
                for (int df = 0; df < 4; ++df)
                  #pragma unroll
                  for (int j = 0; j < 4; ++j)
                    o[mf][df][j] *= sc4[j];
            }

            float ps = 0.f;
            #pragma unroll
            for (int nf = 0; nf < 8; ++nf) {
                float p0 = fexp2(sa[nf][0] * SCL - mrow[mf]);
                float p1 = fexp2(sa[nf][1] * SCL - mrow[mf]);
                float p2 = fexp2(sa[nf][2] * SCL - mrow[mf]);
                float p3 = fexp2(sa[nf][3] * SCL - mrow[mf]);
                ps += (p0 + p1) + (p2 + p3);
                pk[mf][nf * 2 + 0] = cvt_pk_bf16(p0, p1);
                pk[mf][nf * 2 + 1] = cvt_pk_bf16(p2, p3);
            }
            ps += __shfl_xor(ps, 16);
            ps += __shfl_xor(ps, 32);
            lrow[mf] += ps;
        }

        // O += P V : pa[mf] = physkeys [fq*32+8t, +8); vv reused across mf
        #pragma unroll
        for (int t = 0; t < 4; ++t) {
            union { bf8_t v; u32 u[4]; } pa0, pa1;
            #pragma unroll
            for (int i = 0; i < 4; ++i) { pa0.u[i] = pk[0][4 * t + i]; pa1.u[i] = pk[1][4 * t + i]; }
            const int sl = fq * 4 + t;
            #pragma unroll
            for (int df = 0; df < 4; ++df) {
                const int rv = df * 16 + fr;
                const int dsl = sl ^ (rv & 7);
                const bf8_t vv = *(const bf8_t*)&Vs[cur][rv * 128 + dsl * 8];
                o[0][df] = MFMA32(pa0.v, vv, o[0][df]);
                o[1][df] = MFMA32(pa1.v, vv, o[1][df]);
            }
        }
        __syncthreads();
        cur ^= 1;
    }

    const int b = bh >> 4, h = bh & 15;
    #pragma unroll
    for (int mf = 0; mf < 2; ++mf) {
        float ml[4];
        #pragma unroll
        for (int j = 0; j < 4; ++j) ml[j] = __shfl(lrow[mf], fq * 4 + j);
        #pragma unroll
        for (int df = 0; df < 4; ++df)
          #pragma unroll
          for (int j = 0; j < 4; ++j) {
            const int s = q0 + mf * 16 + fq * 4 + j;
            const int dd = df * 16 + fr;
            float v = o[mf][df][j] / ml[j];
            ctx[((size_t)(b * SS + s)) * DM + h * DKH + dd] = f2bf(v);
          }
    }
}

// ---------------- launcher ----------------
extern "C" void kernel_launch(void* const* d_in, const int* in_sizes, int n_in,
                              void* d_out, int out_size, void* d_ws, size_t ws_size,
                              hipStream_t stream)
{
    const float* x     = (const float*)d_in[0];
    const float* W_qkv = (const float*)d_in[1];
    const float* b_qkv = (const float*)d_in[2];
    const float* W_o   = (const float*)d_in[3];
    const float* b_o   = (const float*)d_in[4];
    float* out = (float*)d_out;

    char* ws = (char*)d_ws;
    u16* xb   = (u16*)(ws);                                   // 4096x1024  (8 MB)
    u16* Wqkt = (u16*)(ws + 8388608);                         // 3072x1024  (6 MB)
    u16* Wot  = (u16*)(ws + 8388608 + 6291456);               // 1024x1024  (2 MB)
    u16* Qg   = (u16*)(ws + 16777216);                        // 32x2048x64 (8 MB)
    u16* Kg   = Qg  + 4194304;
    u16* Vg   = Kg  + 4194304;                                // V linear
    u16* Vtg  = Vg  + 4194304;                                // V transposed
    u16* ctx  = xb;                                           // alias: xb dead after k_gemm<0>

    k_prep<<<4608, 256, 0, stream>>>(x, W_qkv, W_o, xb, Wqkt, Wot);
    k_gemm<0, 128, 128><<<dim3(3 * DM / 128, MROWS / 128), 256, 0, stream>>>(
        xb, Wqkt, b_qkv, Qg, Kg, Vg, nullptr, 3 * DM, DM);
    k_vt<<<dim3(SS / 64, BB * NHEADS), 256, 0, stream>>>(Vg, Vtg);
    k_attn<<<dim3(BB * NHEADS, SS / 128), 256, 0, stream>>>(Qg, Kg, Vtg, ctx);
    k_gemm<1, 64, 64><<<dim3(DM / 64, MROWS / 64), 256, 0, stream>>>(
        ctx, Wot, b_o, nullptr, nullptr, nullptr, out, DM, DM);
}